// Round 7
// baseline (114.653 us; speedup 1.0000x reference)
//
#include <hip/hip_runtime.h>

// Depthwise 3x3 conv, NHWC, stride 1, SAME, fp32.
// x: (32,112,112,192), w: (3,3,1,192), b: (192), out: (32,112,112,192)
//
// R7: lean-issue streaming pipeline. Block = 16w x 16c4, 56 output rows
//     (NSTEP=14 tiles of 4). LDS ring = 3 regions of 4 rows x 18 cols x 16c4
//     (1152 f4 = 18 KB each, 55.3 KB total). Per tile: issue next region
//     (18 chunks split 5/5/4/4 across waves), per-wave counted vmcnt
//     (9/9/8/8 steady; stores stay in flight), s_barrier, consume, nt-store.
//     No pad cols, no ghost rows, no prologue duplicates: issued reads
//     drop 495 MB -> 351 MB (fabric-bound at ~7.4 TB/s).

constexpr int Bn = 32, Hn = 112, Wn = 112, Cn = 192, C4 = 48;
constexpr int WT = 16, CT = 16;
constexpr int WTiles = 7, CTiles = 3;
constexpr int NSTEP = 14, HG = 2;     // 56 output rows per block
constexpr int LWC = 18;               // staged halo cols (exactly 16+2)
constexpr int ROWF4 = LWC * CT;       // 288 f4 per staged row
constexpr int REGF4 = 4 * ROWF4;      // 1152 f4 per 4-row region
constexpr int REGB = REGF4 * 16;      // 18432 B
constexpr int NSLOT = 3;              // ring regions (consume 2, land 1)

typedef float floatx4 __attribute__((ext_vector_type(4)));

__device__ __forceinline__ floatx4 fma4(floatx4 a, floatx4 b, floatx4 c) {
  c.x = fmaf(a.x, b.x, c.x);
  c.y = fmaf(a.y, b.y, c.y);
  c.z = fmaf(a.z, b.z, c.z);
  c.w = fmaf(a.w, b.w, c.w);
  return c;
}

__global__ __launch_bounds__(256, 2) void dwconv3x3_stream2(
    const float* __restrict__ x,
    const float* __restrict__ wgt,   // (3,3,1,192)
    const float* __restrict__ bias,  // (192)
    float* __restrict__ out) {
  __shared__ floatx4 lds[NSLOT * REGF4];  // 55296 B
  const int tid = (int)threadIdx.x;
  const int lane = tid & 63;
  const int wave = tid >> 6;

  // Chunked XCD swizzle (1344 % 8 == 0): consecutive sbids share a (b,hg)
  // input stripe -> same XCD L2.
  int bid = blockIdx.x;
  int chk = gridDim.x >> 3;  // 168
  int sbid = (bid & 7) * chk + (bid >> 3);
  int c4t = sbid % CTiles; int tt = sbid / CTiles;
  int wt = tt % WTiles;    tt /= WTiles;
  int hg = tt % HG;        int b = tt / HG;

  const int hbase = hg * (4 * NSTEP);
  const int w0 = wt * WT;
  const int cbase = c4t * (CT * 4);
  const float* xb = x + (long)b * Hn * Wn * Cn;
  const int rstr = Wn * Cn;

  // Steady-state chunk ownership: waves {5,5,4,4} of the 18 region chunks.
  const int cstart = (wave < 2) ? wave * 5 : 10 + (wave - 2) * 4;
  const int ccount = (wave < 2) ? 5 : 4;
  // Per-chunk row-in-region and source column offset (tile-invariant).
  int rr[5];
  int colOff[5];
#pragma unroll
  for (int j = 0; j < 5; ++j) {
    int c = cstart + j;
    int l = c * 64 + lane;
    int r = l / ROWF4;
    int rem = l - r * ROWF4;
    int wi = rem >> 4, c4l = rem & 15;
    int wg = w0 + wi - 1;
    int wc = min(max(wg, 0), Wn - 1);  // clamp; w-validity folded into wv
    rr[j] = r;
    colOff[j] = wc * Cn + cbase + c4l * 4;
  }

  // Prologue: staged rows 0..5 = 2 halo rows (slot 2, rowoffs 2,3; 9 chunks)
  // + region 0 (slot 0; 18 chunks). 27 chunks, stride-4 across waves.
  for (int c = wave; c < 27; c += 4) {
    bool pre = c < 9;
    int cc = pre ? c : c - 9;
    int l = cc * 64 + lane;
    int r = l / ROWF4;
    int rem = l - r * ROWF4;
    int wi = rem >> 4, c4l = rem & 15;
    int row = pre ? r : 2 + r;          // staged row index 0..5
    int h = hbase + row - 1;
    int hc = min(max(h, 0), Hn - 1);
    int wg = w0 + wi - 1;
    int wc = min(max(wg, 0), Wn - 1);
    const float* src = xb + (long)hc * rstr + wc * Cn + cbase + c4l * 4;
    char* dst = (char*)lds +
        (pre ? (2 * REGB + 2 * ROWF4 * 16 + cc * 1024) : (cc * 1024));
    __builtin_amdgcn_global_load_lds(
        (const __attribute__((address_space(1))) void*)src,
        (__attribute__((address_space(3))) void*)dst, 16, 0, 0);
  }

  // Weights (L1-broadcast) with w-edge validity folded in; bias.
  const int c4i = tid & 15;
  const int wi1 = tid >> 4;
  const int cofs = cbase + c4i * 4;
  const int wg1 = w0 + wi1;
  const float cs0 = (wg1 >= 1) ? 1.f : 0.f;
  const float cs2 = (wg1 <= Wn - 2) ? 1.f : 0.f;
  floatx4 wv[3][3];
#pragma unroll
  for (int kh = 0; kh < 3; ++kh) {
#pragma unroll
    for (int kw = 0; kw < 3; ++kw)
      wv[kh][kw] = *(const floatx4*)(wgt + (kh * 3 + kw) * Cn + cofs);
    wv[kh][0] *= cs0;
    wv[kh][2] *= cs2;
  }
  const floatx4 bv = *(const floatx4*)(bias + cofs);
  const float sTop = (hg == 0) ? 0.f : 1.f;
  const float sBot = (hg == HG - 1) ? 0.f : 1.f;

  const int ostr = Wn * C4;  // 5376 f4 per output row
  floatx4* outp = (floatx4*)out +
      ((long)b * Hn + hbase) * ostr + (long)wg1 * C4 + c4t * CT + c4i;
  const int ldaddr = wi1 * CT + c4i;  // f4 offset of (col wi1, this c4)

#pragma unroll
  for (int t = 0; t < NSTEP; ++t) {
    // Issue region t+1 (staged rows 4t+6..4t+9) into slot (t+1)%3 — the one
    // slot not consumed this tile. Skipped on the last tile (no ghosts).
    if (t < NSTEP - 1) {
      char* rbase = (char*)lds + ((t + 1) % 3) * REGB;
      const int R0 = 4 * (t + 1) + 2;  // first staged row of the region
#pragma unroll
      for (int j = 0; j < 5; ++j) {
        if (j < ccount) {  // wave-uniform
          int h = hbase + R0 + rr[j] - 1;   // >= 5, only bottom clamp needed
          int hc = min(h, Hn - 1);
          const float* src = xb + (long)hc * rstr + colOff[j];
          __builtin_amdgcn_global_load_lds(
              (const __attribute__((address_space(1))) void*)src,
              (__attribute__((address_space(3))) void*)(rbase + (cstart + j) * 1024),
              16, 0, 0);
        }
      }
    }
    // Counted per-wave waits: drain exactly what this tile consumes; keep
    // this tile's issued loads (5 or 4) + last tile's 4 stores in flight.
    if (t == 0) {
      if (wave < 2) asm volatile("s_waitcnt vmcnt(5)" ::: "memory");
      else          asm volatile("s_waitcnt vmcnt(4)" ::: "memory");
    } else if (t < NSTEP - 1) {
      if (wave < 2) asm volatile("s_waitcnt vmcnt(9)" ::: "memory");
      else          asm volatile("s_waitcnt vmcnt(8)" ::: "memory");
    } else {
      asm volatile("s_waitcnt vmcnt(4)" ::: "memory");
    }
    __builtin_amdgcn_s_barrier();

    floatx4 acc[4];
#pragma unroll
    for (int o = 0; o < 4; ++o) acc[o] = bv;

    // Consume staged rows 4t..4t+5: rows 4t,4t+1 = region t-1 rowoffs 2,3;
    // rows 4t+2..4t+5 = region t rowoffs 0..3. All offsets compile-time.
#pragma unroll
    for (int r = 0; r < 6; ++r) {
      const int slot = (r < 2) ? (t + 2) % 3 : t % 3;
      const int rowoff = (r < 2) ? r + 2 : r - 2;
      const floatx4* base = lds + slot * REGF4 + rowoff * ROWF4 + ldaddr;
      floatx4 xv0 = base[0];
      floatx4 xv1 = base[CT];
      floatx4 xv2 = base[2 * CT];
      if (t == 0 && r == 0) { xv0 *= sTop; xv1 *= sTop; xv2 *= sTop; }
      if (t == NSTEP - 1 && r == 5) { xv0 *= sBot; xv1 *= sBot; xv2 *= sBot; }
#pragma unroll
      for (int kh = 0; kh < 3; ++kh) {
        int o = r - kh;
        if (o >= 0 && o < 4) {
          acc[o] = fma4(xv0, wv[kh][0], acc[o]);
          acc[o] = fma4(xv1, wv[kh][1], acc[o]);
          acc[o] = fma4(xv2, wv[kh][2], acc[o]);
        }
      }
    }

#pragma unroll
    for (int o = 0; o < 4; ++o)
      __builtin_nontemporal_store(acc[o], outp + (long)(4 * t + o) * ostr);

    // End-of-tile barrier: everyone done reading before next tile's issued
    // loads (placed after this barrier) can land in the recycled slot.
    __builtin_amdgcn_s_barrier();
  }
}

extern "C" void kernel_launch(void* const* d_in, const int* in_sizes, int n_in,
                              void* d_out, int out_size, void* d_ws, size_t ws_size,
                              hipStream_t stream) {
  const float* x = (const float*)d_in[0];
  const float* w = (const float*)d_in[1];
  const float* b = (const float*)d_in[2];
  float* out = (float*)d_out;

  const int grid = Bn * HG * WTiles * CTiles;  // 1344, divisible by 8
  dwconv3x3_stream2<<<grid, 256, 0, stream>>>(x, w, b, out);
}